// Round 2
// baseline (100.133 us; speedup 1.0000x reference)
//
#include <hip/hip_runtime.h>

// B=4, N=4096, D=128 fixed by the reference setup.
// d_ws layout: [0, 4MiB) h as bf16 bits (ushort), [4MiB, +64KiB) sq fp32.

typedef float  f32x4   __attribute__((ext_vector_type(4)));
typedef float  f32x16  __attribute__((ext_vector_type(16)));
typedef short  bf16x8  __attribute__((ext_vector_type(8)));
typedef __attribute__((address_space(3))) void       lds_void_t;
typedef const __attribute__((address_space(1))) void gvoid_t;

__device__ inline float bf2f(unsigned int u) {
    union { unsigned int i; float f; } c; c.i = u << 16; return c.f;
}
__device__ inline unsigned short f2bf(float f) {
    union { float f; unsigned int i; } c; c.f = f;
    unsigned int r = c.i + 0x7fffu + ((c.i >> 16) & 1u);   // RNE
    return (unsigned short)(r >> 16);
}

// ---------------- Kernel A: h = bf16(x @ W^T + b), plus sq[row] = ||h_row||^2 ----
#define KA_ROWS 32
__global__ __launch_bounds__(256) void proj_kernel(
    const float* __restrict__ x, const float* __restrict__ W,
    const float* __restrict__ bias, unsigned short* __restrict__ h,
    float* __restrict__ sq)
{
    __shared__ unsigned short Ws[128][136];   // bf16 bits, padded pitch
    __shared__ float          xs[KA_ROWS][132];
    const int t = threadIdx.x;
    const long r0 = (long)blockIdx.x * KA_ROWS;

    // stage W (fp32 -> bf16) into LDS
    for (int q = t; q < 128 * 128 / 4; q += 256) {
        float4 w4 = ((const float4*)W)[q];
        int e = q >> 5, d = (q & 31) << 2;
        Ws[e][d + 0] = f2bf(w4.x); Ws[e][d + 1] = f2bf(w4.y);
        Ws[e][d + 2] = f2bf(w4.z); Ws[e][d + 3] = f2bf(w4.w);
    }
    // stage x rows (fp32)
    const float4* xsrc = (const float4*)(x + r0 * 128);
    for (int q = t; q < KA_ROWS * 32; q += 256) {
        float4 v = xsrc[q];
        int r = q >> 5, d = (q & 31) << 2;
        xs[r][d] = v.x; xs[r][d + 1] = v.y; xs[r][d + 2] = v.z; xs[r][d + 3] = v.w;
    }
    __syncthreads();

    const int eb = t & 31, rb = t >> 5;
    const int e0 = eb * 4, rr0 = rb * 4;

    float acc_[4][4];
    #pragma unroll
    for (int ei = 0; ei < 4; ++ei) {
        float bv = bias[e0 + ei];
        #pragma unroll
        for (int ri = 0; ri < 4; ++ri) acc_[ri][ei] = bv;
    }

    for (int d = 0; d < 128; d += 4) {
        float wv[4][4];
        #pragma unroll
        for (int ei = 0; ei < 4; ++ei) {
            ushort4 u = *(const ushort4*)&Ws[e0 + ei][d];
            wv[ei][0] = bf2f(u.x); wv[ei][1] = bf2f(u.y);
            wv[ei][2] = bf2f(u.z); wv[ei][3] = bf2f(u.w);
        }
        #pragma unroll
        for (int ri = 0; ri < 4; ++ri) {
            float4 xv = *(const float4*)&xs[rr0 + ri][d];
            #pragma unroll
            for (int ei = 0; ei < 4; ++ei) {
                acc_[ri][ei] = fmaf(xv.x, wv[ei][0],
                               fmaf(xv.y, wv[ei][1],
                               fmaf(xv.z, wv[ei][2],
                               fmaf(xv.w, wv[ei][3], acc_[ri][ei]))));
            }
        }
    }

    float s[4] = {0.f, 0.f, 0.f, 0.f};
    #pragma unroll
    for (int ri = 0; ri < 4; ++ri) {
        ushort4 o;
        float v0 = bf2f(o.x = f2bf(acc_[ri][0]));
        float v1 = bf2f(o.y = f2bf(acc_[ri][1]));
        float v2 = bf2f(o.z = f2bf(acc_[ri][2]));
        float v3 = bf2f(o.w = f2bf(acc_[ri][3]));
        s[ri] = v0 * v0 + v1 * v1 + v2 * v2 + v3 * v3;
        *(ushort4*)&h[(r0 + rr0 + ri) * 128 + e0] = o;
    }
    // reduce over the 32 e-lanes (bits 0..4 of lane id)
    #pragma unroll
    for (int ri = 0; ri < 4; ++ri) {
        #pragma unroll
        for (int m = 16; m > 0; m >>= 1) s[ri] += __shfl_xor(s[ri], m, 64);
    }
    if (eb == 0) {
        #pragma unroll
        for (int ri = 0; ri < 4; ++ri) sq[r0 + rr0 + ri] = s[ri];
    }
}

// ---------------- Kernel B: per 128x128 tile: gram -> exp(-dist) ----------------
// 32x32x16 MFMA so stores are full-line contiguous (col = lane&31).
// LDS XOR-swizzle byte ^= (row&15)<<4, applied at the pre-swizzled global
// source (linear global_load_lds dest) AND the ds_read address (rule #21).
__global__ __launch_bounds__(256) void gram_kernel(
    const unsigned short* __restrict__ h, const float* __restrict__ sq,
    float* __restrict__ out)
{
    __shared__ __align__(16) unsigned short hs[2][128 * 128]; // 64 KiB
    const int bid = blockIdx.x;
    const int bb = bid >> 10;
    const int it = (bid >> 5) & 31, jt = bid & 31;
    const int i0 = bb * 4096 + it * 128;
    const int j0 = bb * 4096 + jt * 128;
    const int t = threadIdx.x, w = t >> 6, lane = t & 63;

    const char* hb = (const char*)h;
    #pragma unroll
    for (int q = 0; q < 8; ++q) {
        int p   = ((w * 8 + q) << 10) + (lane << 4);  // linear byte offset in tile
        int row = p >> 8;                              // 256 B per row
        int c   = (p >> 4) & 15;                       // 16 B chunk in row
        int cs  = c ^ (row & 15);                      // inverse swizzle at source
        const void* srcA = hb + ((long)(i0 + row) << 8) + (cs << 4);
        const void* srcB = hb + ((long)(j0 + row) << 8) + (cs << 4);
        unsigned off = (unsigned)((w * 8 + q) << 10);  // wave-uniform LDS base
        __builtin_amdgcn_global_load_lds((gvoid_t*)srcA,
            (lds_void_t*)(((char*)&hs[0][0]) + off), 16, 0, 0);
        __builtin_amdgcn_global_load_lds((gvoid_t*)srcB,
            (lds_void_t*)(((char*)&hs[1][0]) + off), 16, 0, 0);
    }
    __syncthreads();

    const int wr = w >> 1, wc = w & 1;      // wave -> 64x64 quadrant
    const int l31 = lane & 31, lh = lane >> 5;
    f32x16 acc[2][2] = {};
    const char* h0 = (const char*)&hs[0][0];
    const char* h1 = (const char*)&hs[1][0];

    #pragma unroll
    for (int ks = 0; ks < 8; ++ks) {        // K = 8 x 16
        bf16x8 af[2], bg[2];
        #pragma unroll
        for (int rb = 0; rb < 2; ++rb) {
            int rowA = wr * 64 + rb * 32 + l31;
            int cA = ((ks * 2 + lh) ^ (rowA & 15)) << 4;
            af[rb] = *(const bf16x8*)(h0 + (rowA << 8) + cA);
            int rowB = wc * 64 + rb * 32 + l31;
            int cB = ((ks * 2 + lh) ^ (rowB & 15)) << 4;
            bg[rb] = *(const bf16x8*)(h1 + (rowB << 8) + cB);
        }
        #pragma unroll
        for (int rb = 0; rb < 2; ++rb)
            #pragma unroll
            for (int nb = 0; nb < 2; ++nb)
                acc[rb][nb] = __builtin_amdgcn_mfma_f32_32x32x16_bf16(
                    af[rb], bg[nb], acc[rb][nb], 0, 0, 0);
    }

    // epilogue: d2 = sq_i + sq_j - 2*gram; out = exp(-sqrt(max(d2,0)))
    float sqj_r[2];
    #pragma unroll
    for (int nb = 0; nb < 2; ++nb) sqj_r[nb] = sq[j0 + wc * 64 + nb * 32 + l31];

    #pragma unroll
    for (int rb = 0; rb < 2; ++rb) {
        #pragma unroll
        for (int reg = 0; reg < 16; ++reg) {
            int il = wr * 64 + rb * 32 + (reg & 3) + 8 * (reg >> 2) + 4 * lh;
            float sqi_v = sq[i0 + il];
            #pragma unroll
            for (int nb = 0; nb < 2; ++nb) {
                int jl = wc * 64 + nb * 32 + l31;   // 32 consecutive cols in 32 lanes
                float g  = acc[rb][nb][reg];
                float d2 = fmaxf(sqi_v + sqj_r[nb] - 2.0f * g, 0.0f);
                float val = __expf(-sqrtf(d2));
                if (it == jt && il == jl) val = 1.0f;     // exact diagonal
                out[((long)(i0 + il) << 12) + (jt << 7) + jl] = val;
            }
        }
    }
}

extern "C" void kernel_launch(void* const* d_in, const int* in_sizes, int n_in,
                              void* d_out, int out_size, void* d_ws, size_t ws_size,
                              hipStream_t stream) {
    const float* x = (const float*)d_in[0];   // [4,4096,128]
    const float* W = (const float*)d_in[1];   // [128,128]
    const float* b = (const float*)d_in[2];   // [128]
    float* out = (float*)d_out;               // [4,4096,4096]

    unsigned short* h = (unsigned short*)d_ws;                       // 16384*128 bf16
    float* sq = (float*)((char*)d_ws + (size_t)16384 * 128 * 2);     // 16384 fp32

    proj_kernel<<<dim3(16384 / KA_ROWS), dim3(256), 0, stream>>>(x, W, b, h, sq);
    gram_kernel<<<dim3(4096), dim3(256), 0, stream>>>(h, sq, out);
}

// Round 3
// 96.352 us; speedup vs baseline: 1.0392x; 1.0392x over previous
//
#include <hip/hip_runtime.h>

// B=4, N=4096, D=128 fixed by the reference setup.
// d_ws layout: [0, 4MiB) h as bf16 bits (ushort), [4MiB, +64KiB) sq fp32.

typedef float  f32x4   __attribute__((ext_vector_type(4)));
typedef float  f32x16  __attribute__((ext_vector_type(16)));
typedef short  bf16x8  __attribute__((ext_vector_type(8)));
typedef __attribute__((address_space(3))) void       lds_void_t;
typedef const __attribute__((address_space(1))) void gvoid_t;

__device__ inline float bf2f(unsigned int u) {
    union { unsigned int i; float f; } c; c.i = u << 16; return c.f;
}
__device__ inline unsigned short f2bf(float f) {
    union { float f; unsigned int i; } c; c.f = f;
    unsigned int r = c.i + 0x7fffu + ((c.i >> 16) & 1u);   // RNE
    return (unsigned short)(r >> 16);
}

// ---------------- Kernel A: h = bf16(x @ W^T + b), plus sq[row] = ||h_row||^2 ----
#define KA_ROWS 32
__global__ __launch_bounds__(256) void proj_kernel(
    const float* __restrict__ x, const float* __restrict__ W,
    const float* __restrict__ bias, unsigned short* __restrict__ h,
    float* __restrict__ sq)
{
    __shared__ unsigned short Ws[128][136];   // bf16 bits, padded pitch
    __shared__ float          xs[KA_ROWS][132];
    const int t = threadIdx.x;
    const long r0 = (long)blockIdx.x * KA_ROWS;

    // stage W (fp32 -> bf16) into LDS
    for (int q = t; q < 128 * 128 / 4; q += 256) {
        float4 w4 = ((const float4*)W)[q];
        int e = q >> 5, d = (q & 31) << 2;
        Ws[e][d + 0] = f2bf(w4.x); Ws[e][d + 1] = f2bf(w4.y);
        Ws[e][d + 2] = f2bf(w4.z); Ws[e][d + 3] = f2bf(w4.w);
    }
    // stage x rows (fp32)
    const float4* xsrc = (const float4*)(x + r0 * 128);
    for (int q = t; q < KA_ROWS * 32; q += 256) {
        float4 v = xsrc[q];
        int r = q >> 5, d = (q & 31) << 2;
        xs[r][d] = v.x; xs[r][d + 1] = v.y; xs[r][d + 2] = v.z; xs[r][d + 3] = v.w;
    }
    __syncthreads();

    const int eb = t & 31, rb = t >> 5;
    const int e0 = eb * 4, rr0 = rb * 4;

    float acc_[4][4];
    #pragma unroll
    for (int ei = 0; ei < 4; ++ei) {
        float bv = bias[e0 + ei];
        #pragma unroll
        for (int ri = 0; ri < 4; ++ri) acc_[ri][ei] = bv;
    }

    for (int d = 0; d < 128; d += 4) {
        float wv[4][4];
        #pragma unroll
        for (int ei = 0; ei < 4; ++ei) {
            ushort4 u = *(const ushort4*)&Ws[e0 + ei][d];
            wv[ei][0] = bf2f(u.x); wv[ei][1] = bf2f(u.y);
            wv[ei][2] = bf2f(u.z); wv[ei][3] = bf2f(u.w);
        }
        #pragma unroll
        for (int ri = 0; ri < 4; ++ri) {
            float4 xv = *(const float4*)&xs[rr0 + ri][d];
            #pragma unroll
            for (int ei = 0; ei < 4; ++ei) {
                acc_[ri][ei] = fmaf(xv.x, wv[ei][0],
                               fmaf(xv.y, wv[ei][1],
                               fmaf(xv.z, wv[ei][2],
                               fmaf(xv.w, wv[ei][3], acc_[ri][ei]))));
            }
        }
    }

    float s[4] = {0.f, 0.f, 0.f, 0.f};
    #pragma unroll
    for (int ri = 0; ri < 4; ++ri) {
        ushort4 o;
        float v0 = bf2f(o.x = f2bf(acc_[ri][0]));
        float v1 = bf2f(o.y = f2bf(acc_[ri][1]));
        float v2 = bf2f(o.z = f2bf(acc_[ri][2]));
        float v3 = bf2f(o.w = f2bf(acc_[ri][3]));
        s[ri] = v0 * v0 + v1 * v1 + v2 * v2 + v3 * v3;
        *(ushort4*)&h[(r0 + rr0 + ri) * 128 + e0] = o;
    }
    // reduce over the 32 e-lanes (bits 0..4 of lane id)
    #pragma unroll
    for (int ri = 0; ri < 4; ++ri) {
        #pragma unroll
        for (int m = 16; m > 0; m >>= 1) s[ri] += __shfl_xor(s[ri], m, 64);
    }
    if (eb == 0) {
        #pragma unroll
        for (int ri = 0; ri < 4; ++ri) sq[r0 + rr0 + ri] = s[ri];
    }
}

// ---------------- Kernel B: per 128x128 tile: gram -> exp(-dist) ----------------
// 32x32x16 MFMA; full-line contiguous stores (col = lane&31), emitted as
// NON-TEMPORAL so the 268 MB out-stream doesn't evict the hot 4 MiB h buffer
// from L2/L3 (theory: h re-reads were falling through to HBM, ~536 MB total).
__global__ __launch_bounds__(256) void gram_kernel(
    const unsigned short* __restrict__ h, const float* __restrict__ sq,
    float* __restrict__ out)
{
    __shared__ __align__(16) unsigned short hs[2][128 * 128]; // 64 KiB
    const int bid = blockIdx.x;
    const int bb = bid >> 10;
    const int it = (bid >> 5) & 31, jt = bid & 31;
    const int i0 = bb * 4096 + it * 128;
    const int j0 = bb * 4096 + jt * 128;
    const int t = threadIdx.x, w = t >> 6, lane = t & 63;

    const char* hb = (const char*)h;
    #pragma unroll
    for (int q = 0; q < 8; ++q) {
        int p   = ((w * 8 + q) << 10) + (lane << 4);  // linear byte offset in tile
        int row = p >> 8;                              // 256 B per row
        int c   = (p >> 4) & 15;                       // 16 B chunk in row
        int cs  = c ^ (row & 15);                      // inverse swizzle at source
        const void* srcA = hb + ((long)(i0 + row) << 8) + (cs << 4);
        const void* srcB = hb + ((long)(j0 + row) << 8) + (cs << 4);
        unsigned off = (unsigned)((w * 8 + q) << 10);  // wave-uniform LDS base
        __builtin_amdgcn_global_load_lds((gvoid_t*)srcA,
            (lds_void_t*)(((char*)&hs[0][0]) + off), 16, 0, 0);
        __builtin_amdgcn_global_load_lds((gvoid_t*)srcB,
            (lds_void_t*)(((char*)&hs[1][0]) + off), 16, 0, 0);
    }
    __syncthreads();

    const int wr = w >> 1, wc = w & 1;      // wave -> 64x64 quadrant
    const int l31 = lane & 31, lh = lane >> 5;
    f32x16 acc[2][2] = {};
    const char* h0 = (const char*)&hs[0][0];
    const char* h1 = (const char*)&hs[1][0];

    #pragma unroll
    for (int ks = 0; ks < 8; ++ks) {        // K = 8 x 16
        bf16x8 af[2], bg[2];
        #pragma unroll
        for (int rb = 0; rb < 2; ++rb) {
            int rowA = wr * 64 + rb * 32 + l31;
            int cA = ((ks * 2 + lh) ^ (rowA & 15)) << 4;
            af[rb] = *(const bf16x8*)(h0 + (rowA << 8) + cA);
            int rowB = wc * 64 + rb * 32 + l31;
            int cB = ((ks * 2 + lh) ^ (rowB & 15)) << 4;
            bg[rb] = *(const bf16x8*)(h1 + (rowB << 8) + cB);
        }
        #pragma unroll
        for (int rb = 0; rb < 2; ++rb)
            #pragma unroll
            for (int nb = 0; nb < 2; ++nb)
                acc[rb][nb] = __builtin_amdgcn_mfma_f32_32x32x16_bf16(
                    af[rb], bg[nb], acc[rb][nb], 0, 0, 0);
    }

    // epilogue: d2 = sq_i + sq_j - 2*gram; out = exp(-sqrt(max(d2,0)))
    float sqj_r[2];
    #pragma unroll
    for (int nb = 0; nb < 2; ++nb) sqj_r[nb] = sq[j0 + wc * 64 + nb * 32 + l31];

    #pragma unroll
    for (int rb = 0; rb < 2; ++rb) {
        #pragma unroll
        for (int reg = 0; reg < 16; ++reg) {
            int il = wr * 64 + rb * 32 + (reg & 3) + 8 * (reg >> 2) + 4 * lh;
            float sqi_v = sq[i0 + il];
            #pragma unroll
            for (int nb = 0; nb < 2; ++nb) {
                int jl = wc * 64 + nb * 32 + l31;   // 32 consecutive cols in 32 lanes
                float g  = acc[rb][nb][reg];
                float d2 = fmaxf(sqi_v + sqj_r[nb] - 2.0f * g, 0.0f);
                float val = __expf(-sqrtf(d2));
                if (it == jt && il == jl) val = 1.0f;     // exact diagonal
                __builtin_nontemporal_store(
                    val, &out[((long)(i0 + il) << 12) + (jt << 7) + jl]);
            }
        }
    }
}

extern "C" void kernel_launch(void* const* d_in, const int* in_sizes, int n_in,
                              void* d_out, int out_size, void* d_ws, size_t ws_size,
                              hipStream_t stream) {
    const float* x = (const float*)d_in[0];   // [4,4096,128]
    const float* W = (const float*)d_in[1];   // [128,128]
    const float* b = (const float*)d_in[2];   // [128]
    float* out = (float*)d_out;               // [4,4096,4096]

    unsigned short* h = (unsigned short*)d_ws;                       // 16384*128 bf16
    float* sq = (float*)((char*)d_ws + (size_t)16384 * 128 * 2);     // 16384 fp32

    proj_kernel<<<dim3(16384 / KA_ROWS), dim3(256), 0, stream>>>(x, W, b, h, sq);
    gram_kernel<<<dim3(4096), dim3(256), 0, stream>>>(h, sq, out);
}